// Round 20
// baseline (48.520 us; speedup 1.0000x reference)
//
#include <hip/hip_runtime.h>
#include <math.h>

#define HWDIM 96
#define NPIX (HWDIM*HWDIM)     // 9216
#define BATCH 2
#define CIN 64
#define CCAT 128

typedef __attribute__((ext_vector_type(8))) short bf16x8;
typedef __attribute__((ext_vector_type(4))) float f32x4;

__device__ __forceinline__ unsigned short f2bf(float f) {
    unsigned u = __builtin_bit_cast(unsigned, f);
    unsigned r = (u + 0x7FFFu + ((u >> 16) & 1u)) >> 16;
    return (unsigned short)r;
}

// ---------------------------------------------------------------------------
// Kernel B: conv + inline pad + inline weight transpose (flag handshake).
// grid (192,2). Blocks (y==0, bx<36) write wbT (write-through agent stores),
// then release-add the flag; all blocks stage x->LDS (overlapping), then
// acquire-spin until flag==36 before touching wbT. All 384 blocks co-resident
// (42.3KB LDS -> >=2 blocks/CU -> 512 slots), so the spin cannot deadlock.
// ---------------------------------------------------------------------------
__global__ __launch_bounds__(256, 2) void conv_all(
        const float* __restrict__ x,
        const float* __restrict__ wq, const float* __restrict__ wk,
        const float* __restrict__ wv,
        const float* __restrict__ bq, const float* __restrict__ bk,
        const float* __restrict__ bv,
        unsigned short* __restrict__ wbT, unsigned* __restrict__ flag,
        unsigned short* __restrict__ Qb, unsigned short* __restrict__ Kb,
        unsigned short* __restrict__ Vb) {
    __shared__ unsigned short xs[3 * 98 * 72];   // 42336 B (reused as [96][136])
    int bx      = blockIdx.x;                    // 0..191
    int spatial = (bx & 7) * 24 + (bx >> 3);     // XCD-aligned; 24 rows per XCD
    int b    = spatial / 96;
    int h    = spatial % 96;
    int co0  = blockIdx.y * 128;
    int tid  = threadIdx.x;

    // ---- weight transpose by 36 blocks: 73728 u32 pairs, 2048/block ----
    if (blockIdx.y == 0 && bx < 36) {
        int base = bx * 2048;
        #pragma unroll
        for (int e = 0; e < 8; ++e) {
            int idx2 = base + e * 256 + tid;     // < 73728
            int t    = idx2 / 8192;
            int rem  = idx2 % 8192;
            int co   = rem >> 5;
            int ci2  = rem & 31;
            int ci   = ci2 * 2;
            float v0, v1;
            if (co < 64)       { v0 = wq[(co * 64 + ci) * 9 + t];        v1 = wq[(co * 64 + ci + 1) * 9 + t]; }
            else if (co < 128) { v0 = wk[((co - 64) * 64 + ci) * 9 + t]; v1 = wk[((co - 64) * 64 + ci + 1) * 9 + t]; }
            else               { v0 = wv[((co - 128) * 64 + ci) * 9 + t]; v1 = wv[((co - 128) * 64 + ci + 1) * 9 + t]; }
            unsigned pack = (unsigned)f2bf(v0) | ((unsigned)f2bf(v1) << 16);
            __hip_atomic_store((unsigned*)&wbT[(t * 256 + co) * 64 + ci], pack,
                               __ATOMIC_RELAXED, __HIP_MEMORY_SCOPE_AGENT);
        }
        __syncthreads();
        if (tid == 0)
            __hip_atomic_fetch_add(flag, 1u, __ATOMIC_RELEASE, __HIP_MEMORY_SCOPE_AGENT);
    }

    // ---- stage 3 rows x 96 interior px from x (float4), halo cols = 0 ----
    #pragma unroll
    for (int g = 0; g < 18; ++g) {
        int i   = tid + g * 256;                 // < 4608
        int r   = i / 1536;
        int rem = i % 1536;
        int ci  = rem / 24;
        int p4  = rem % 24;
        int iy  = h - 1 + r;
        float4 v = make_float4(0.f, 0.f, 0.f, 0.f);
        if (iy >= 0 && iy < HWDIM)
            v = *(const float4*)&x[((b * CIN + ci) * HWDIM + iy) * HWDIM + p4 * 4];
        int bse = (r * 98 + 1 + p4 * 4) * 72 + ci;
        xs[bse]       = f2bf(v.x);
        xs[bse + 72]  = f2bf(v.y);
        xs[bse + 144] = f2bf(v.z);
        xs[bse + 216] = f2bf(v.w);
    }
    if (tid < 192) {   // px 0 and 97 are always outside the image -> zero
        #pragma unroll
        for (int e = 0; e < 2; ++e) {
            int ii  = tid + e * 192;             // < 384
            int r   = ii / 128;
            int rem = ii % 128;
            int ci  = rem >> 1;
            int px  = (rem & 1) ? 97 : 0;
            xs[(r * 98 + px) * 72 + ci] = 0;
        }
    }

    // ---- wait for wbT (staging latency hides most of it) ----
    if (tid == 0) {
        while (__hip_atomic_load(flag, __ATOMIC_ACQUIRE, __HIP_MEMORY_SCOPE_AGENT) < 36u)
            __builtin_amdgcn_s_sleep(8);
    }
    __syncthreads();

    int lane = tid & 63;
    int wv_  = tid >> 6;
    int lw   = lane & 15;
    int ksub = (lane >> 4) * 8;
    int co_t = co0 + wv_ * 32;

    f32x4 acc[6][2];
    #pragma unroll
    for (int m = 0; m < 6; ++m)
        #pragma unroll
        for (int n = 0; n < 2; ++n) acc[m][n] = (f32x4){0.f, 0.f, 0.f, 0.f};

    #pragma unroll
    for (int half = 0; half < 2; ++half) {
        bf16x8 Bf[9][2];
        #pragma unroll
        for (int t = 0; t < 9; ++t) {
            const unsigned short* bp = wbT + ((t * 256 + co_t + lw) * 64) + half * 32 + ksub;
            Bf[t][0] = *(const bf16x8*)(bp);
            Bf[t][1] = *(const bf16x8*)(bp + 16 * 64);
        }
        #pragma unroll
        for (int t = 0; t < 9; ++t) {
            int kh = t / 3, kw = t % 3;
            const unsigned short* ap = xs + (kh * 98 + lw + kw) * 72 + half * 32 + ksub;
            #pragma unroll
            for (int m = 0; m < 6; ++m) {
                bf16x8 A = *(const bf16x8*)(ap + (m * 16) * 72);
                acc[m][0] = __builtin_amdgcn_mfma_f32_16x16x32_bf16(A, Bf[t][0], acc[m][0], 0, 0, 0);
                acc[m][1] = __builtin_amdgcn_mfma_f32_16x16x32_bf16(A, Bf[t][1], acc[m][1], 0, 0, 0);
            }
        }
    }

    // ---- epilogue: bias + f2bf into LDS bounce [96 px][136], b128 stores ----
    __syncthreads();                 // xs reads complete; reuse as xs2
    unsigned short* xs2 = xs;        // [96][136]
    #pragma unroll
    for (int n = 0; n < 2; ++n) {
        int co_f = co_t + n * 16 + lw;
        float bval;
        if (co_f < 64)       bval = bq[co_f];
        else if (co_f < 128) bval = bk[co_f - 64];
        else                 bval = bv[co_f - 128];
        int chl = wv_ * 32 + n * 16 + lw;
        #pragma unroll
        for (int m = 0; m < 6; ++m) {
            int px = m * 16 + ((lane >> 4) << 2);
            #pragma unroll
            for (int r = 0; r < 4; ++r)
                xs2[(px + r) * 136 + chl] = f2bf(acc[m][n][r] + bval);
        }
    }
    __syncthreads();

    #pragma unroll
    for (int e = 0; e < 6; ++e) {
        int i   = tid + e * 256;
        int px  = i >> 4;
        int seg = i & 15;
        uint4 v = *(uint4*)&xs2[px * 136 + seg * 8];
        int pix = b * NPIX + h * HWDIM + px;
        int chl = seg * 8;
        if (co0 == 0) {
            if (chl < 64) *(uint4*)&Qb[pix * CCAT + chl]        = v;
            else          *(uint4*)&Kb[pix * CCAT + (chl - 64)] = v;
        } else {
            *(uint4*)&Vb[pix * CCAT + chl] = v;
        }
    }

    // positional encoding (ch 64..127 of Qb and Kb) by y==0 blocks: 96x64
    if (blockIdx.y == 0) {
        #pragma unroll
        for (int e = 0; e < 24; ++e) {
            int i  = tid + e * 256;          // < 6144
            int c  = i & 63;
            int w  = i >> 6;
            int pos = (c < 32) ? h : w;
            int j   = c & 15;
            float f   = exp2f(-(float)j * 0.83048202372184059f);
            float ang = (float)pos * f;
            float val = ((c & 16) == 0) ? __sinf(ang) : __cosf(ang);
            unsigned short bvv = f2bf(val);
            int pix = b * NPIX + h * HWDIM + w;
            Qb[pix * CCAT + 64 + c] = bvv;
            Kb[pix * CCAT + 64 + c] = bvv;
        }
    }
}

// ---------------------------------------------------------------------------
// Kernel C: natt (champion, byte-identical to R19)
// ---------------------------------------------------------------------------
#define KPAD 136   // bf16 row pad (272 B, 16B-aligned)
#define LGP  114   // f32 logit row stride; MUST be >= 112

__global__ __launch_bounds__(256, 3) void natt_mfma(
        const unsigned short* __restrict__ Qb,
        const unsigned short* __restrict__ Kb,
        const unsigned short* __restrict__ Vb,
        float* __restrict__ out) {
    __shared__ unsigned short Vt[128 * KPAD];   // 34816 B  Vt[ch][nbr^swz]
    __shared__ unsigned short Pb[16 * KPAD];    //  4352 B  Pb[q][nbr]
    __shared__ float Lg[16 * LGP];              //  7296 B   -> 46464 B total

    int bid  = blockIdx.x;                 // 0..1151
    int xcd  = bid & 7;
    int slot = bid >> 3;                   // 0..143
    int s3   = slot % 3;
    int rest = slot / 3;                   // 0..47
    int code = xcd * 3 + s3;               // 0..23
    int b  = code / 12;
    int th = code % 12;
    int tw = rest % 12;
    int gg = rest / 12;                    // 0..3
    int gh = gg & 1;
    int gw = gg >> 1;

    int rh0 = th * 4, rw0 = tw * 4;
    int base_h = min(max(rh0 - 3, 0), 41);
    int base_w = min(max(rw0 - 3, 0), 41);
    int tid = threadIdx.x;
    int lane = tid & 63;
    int wv   = tid >> 6;
    int lw   = lane & 15;
    int ks8  = (lane >> 4) * 8;

    // ---- issue V loads first (consumed after QK^T: latency hidden) ----
    uint4 va[4], vb2[4];
    int   vdst[4];
    #pragma unroll
    for (int j = 0; j < 4; ++j) {
        int c = tid + j * 256;
        bool valid = (j < 3) || (tid < 32);
        int pp = c >> 4, c8 = c & 15;
        int px0 = pp * 2, px1 = px0 + 1;
        int ih0 = px0 / 10, iw0 = px0 - ih0 * 10;
        int ih1 = px1 / 10, iw1 = px1 - ih1 * 10;
        int gp0 = b * NPIX + (gh + 2 * min(base_h + ih0, 47)) * HWDIM + (gw + 2 * min(base_w + iw0, 47));
        int gp1 = b * NPIX + (gh + 2 * min(base_h + ih1, 47)) * HWDIM + (gw + 2 * min(base_w + iw1, 47));
        if (valid) {
            va[j]  = *(const uint4*)(Vb + gp0 * CCAT + c8 * 8);
            vb2[j] = *(const uint4*)(Vb + gp1 * CCAT + c8 * 8);
        }
        vdst[j] = (c8 * 8) * KPAD + (px0 ^ ((c8 & 7) << 3));
    }

    // ---- zero Vt cols 64..127 ----
    for (int i = tid; i < 1024; i += 256) {
        int row = i >> 3, sg = i & 7;
        *(uint4*)(Vt + row * KPAD + 64 + sg * 8) = (uint4){0, 0, 0, 0};
    }

    // ---- QK^T: A (Q row lw) and B (K rows) fragments direct from global ----
    const float scale = 0.08838834764831845f;
    {
        int qi = lw >> 2, qj = lw & 3;
        const unsigned short* qsrc = Qb +
            ((b * NPIX + (gh + 2 * (rh0 + qi)) * HWDIM + (gw + 2 * (rw0 + qj))) * CCAT) + ks8;
        bf16x8 A0 = *(const bf16x8*)(qsrc);
        bf16x8 A1 = *(const bf16x8*)(qsrc + 32);
        bf16x8 A2 = *(const bf16x8*)(qsrc + 64);
        bf16x8 A3 = *(const bf16x8*)(qsrc + 96);

        #pragma unroll
        for (int tt = 0; tt < 2; ++tt) {
            int tile = wv + tt * 4;
            if (tile < 7) {
                int px = min(tile * 16 + lw, 99);
                int ih = px / 10, iw = px - ih * 10;
                const unsigned short* ksrc = Kb +
                    ((b * NPIX + (gh + 2 * min(base_h + ih, 47)) * HWDIM
                               + (gw + 2 * min(base_w + iw, 47))) * CCAT) + ks8;
                bf16x8 B0 = *(const bf16x8*)(ksrc);
                bf16x8 B1 = *(const bf16x8*)(ksrc + 32);
                bf16x8 B2 = *(const bf16x8*)(ksrc + 64);
                bf16x8 B3 = *(const bf16x8*)(ksrc + 96);
                f32x4 acc = (f32x4){0.f, 0.f, 0.f, 0.f};
                __builtin_amdgcn_s_setprio(1);
                acc = __builtin_amdgcn_mfma_f32_16x16x32_bf16(A0, B0, acc, 0, 0, 0);
                acc = __builtin_amdgcn_mfma_f32_16x16x32_bf16(A1, B1, acc, 0, 0, 0);
                acc = __builtin_amdgcn_mfma_f32_16x16x32_bf16(A2, B2, acc, 0, 0, 0);
                acc = __builtin_amdgcn_mfma_f32_16x16x32_bf16(A3, B3, acc, 0, 0, 0);
                __builtin_amdgcn_s_setprio(0);
                #pragma unroll
                for (int r = 0; r < 4; ++r) {
                    int m = (lane >> 4) * 4 + r;
                    Lg[m * LGP + tile * 16 + lw] = acc[r] * scale;
                }
            }
        }
    }
    __syncthreads();   // barrier #0: Lg complete; Vt-zero complete

    // ---- V-pack into Vt ----
    #pragma unroll
    for (int j = 0; j < 4; ++j) {
        bool valid = (j < 3) || (tid < 32);
        if (valid) {
            unsigned short* vp = Vt + vdst[j];
            uint4 v0 = va[j], v1 = vb2[j];
            *(unsigned*)(vp + 0 * KPAD) = (v0.x & 0xFFFFu) | (v1.x << 16);
            *(unsigned*)(vp + 1 * KPAD) = (v0.x >> 16)     | (v1.x & 0xFFFF0000u);
            *(unsigned*)(vp + 2 * KPAD) = (v0.y & 0xFFFFu) | (v1.y << 16);
            *(unsigned*)(vp + 3 * KPAD) = (v0.y >> 16)     | (v1.y & 0xFFFF0000u);
            *(unsigned*)(vp + 4 * KPAD) = (v0.z & 0xFFFFu) | (v1.z << 16);
            *(unsigned*)(vp + 5 * KPAD) = (v0.z >> 16)     | (v1.z & 0xFFFF0000u);
            *(unsigned*)(vp + 6 * KPAD) = (v0.w & 0xFFFFu) | (v1.w << 16);
            *(unsigned*)(vp + 7 * KPAD) = (v0.w >> 16)     | (v1.w & 0xFFFF0000u);
        }
    }

    // ---- softmax (16 threads per query) -> Pb bf16 ----
    int q   = tid >> 4, k16 = tid & 15;
    {
        int qi  = q >> 2, qj = q & 3;
        int rh  = rh0 + qi, rw = rw0 + qj;
        int oh  = min(max(rh - 3, 0), 41) - base_h;
        int ow  = min(max(rw - 3, 0), 41) - base_w;

        float ev[4];
        int   en[4];
        float mx = -1e30f;
        #pragma unroll
        for (int u = 0; u < 4; ++u) {
            int idx = k16 + u * 16;
            if (idx < 49) {
                int i = idx / 7, j = idx - i * 7;
                int n = (oh + i) * 10 + ow + j;
                en[u] = n;
                float l = Lg[q * LGP + n];
                ev[u] = l;
                mx = fmaxf(mx, l);
            } else { en[u] = -1; ev[u] = 0.f; }
        }
        #pragma unroll
        for (int off = 8; off > 0; off >>= 1) mx = fmaxf(mx, __shfl_xor(mx, off));
        float s = 0.f;
        #pragma unroll
        for (int u = 0; u < 4; ++u)
            if (en[u] >= 0) { ev[u] = __expf(ev[u] - mx); s += ev[u]; }
        #pragma unroll
        for (int off = 8; off > 0; off >>= 1) s += __shfl_xor(s, off);
        float rs = 1.0f / s;
        *(uint4*)(Pb + q * KPAD + k16 * 8) = (uint4){0, 0, 0, 0};
        #pragma unroll
        for (int u = 0; u < 4; ++u)
            if (en[u] >= 0) Pb[q * KPAD + en[u]] = f2bf(ev[u] * rs);
    }
    __syncthreads();   // barrier #1: Pb and Vt ready

    // ---- PV MFMA: wave handles ch-tiles 2wv, 2wv+1 ----
    bf16x8 A4[4];
    #pragma unroll
    for (int kk = 0; kk < 4; ++kk)
        A4[kk] = *(const bf16x8*)(Pb + lw * KPAD + kk * 32 + ks8);

    __builtin_amdgcn_s_setprio(1);
    #pragma unroll
    for (int tt = 0; tt < 2; ++tt) {
        int tile = wv * 2 + tt;
        int row  = tile * 16 + lw;
        int sw   = ((row >> 3) & 7) << 3;
        const unsigned short* vrow = Vt + row * KPAD;
        f32x4 acc = (f32x4){0.f, 0.f, 0.f, 0.f};
        #pragma unroll
        for (int kk = 0; kk < 4; ++kk) {
            bf16x8 Bf = *(const bf16x8*)(vrow + ((kk * 32 + ks8) ^ sw));
            acc = __builtin_amdgcn_mfma_f32_16x16x32_bf16(A4[kk], Bf, acc, 0, 0, 0);
        }
        int ch = row;
        #pragma unroll
        for (int r = 0; r < 4; ++r) {
            int qq = (lane >> 4) * 4 + r;
            int qi = qq >> 2, qj = qq & 3;
            int gp = b * NPIX + (gh + 2 * (rh0 + qi)) * HWDIM + (gw + 2 * (rw0 + qj));
            out[gp * CCAT + ch] = acc[r];
        }
    }
    __builtin_amdgcn_s_setprio(0);
}

// ---------------------------------------------------------------------------
extern "C" void kernel_launch(void* const* d_in, const int* in_sizes, int n_in,
                              void* d_out, int out_size, void* d_ws, size_t ws_size,
                              hipStream_t stream) {
    const float* x  = (const float*)d_in[0];
    const float* wq = (const float*)d_in[1];
    const float* bq = (const float*)d_in[2];
    const float* wk = (const float*)d_in[3];
    const float* bk = (const float*)d_in[4];
    const float* wv = (const float*)d_in[5];
    const float* bv = (const float*)d_in[6];

    unsigned short* ws = (unsigned short*)d_ws;
    unsigned short* Qb  = ws;                              // 2359296 bf16
    unsigned short* Kb  = Qb + BATCH * NPIX * CCAT;
    unsigned short* Vb  = Kb + BATCH * NPIX * CCAT;
    unsigned short* wbT = Vb + BATCH * NPIX * CCAT;        // 147456 bf16
    unsigned*       flag = (unsigned*)(wbT + 147456);      // 4B, 4B-aligned

    hipMemsetAsync(flag, 0, 4, stream);
    hipLaunchKernelGGL(conv_all, dim3(192, 2), dim3(256), 0, stream,
                       x, wq, wk, wv, bq, bk, bv, wbT, flag, Qb, Kb, Vb);
    hipLaunchKernelGGL(natt_mfma, dim3(1152), dim3(256), 0, stream,
                       Qb, Kb, Vb, (float*)d_out);
}

// Round 21
// 43.430 us; speedup vs baseline: 1.1172x; 1.1172x over previous
//
#include <hip/hip_runtime.h>
#include <math.h>

#define HWDIM 96
#define NPIX (HWDIM*HWDIM)     // 9216
#define BATCH 2
#define CIN 64
#define CCAT 128

typedef __attribute__((ext_vector_type(8))) short bf16x8;
typedef __attribute__((ext_vector_type(4))) float f32x4;

__device__ __forceinline__ unsigned short f2bf(float f) {
    unsigned u = __builtin_bit_cast(unsigned, f);
    unsigned r = (u + 0x7FFFu + ((u >> 16) & 1u)) >> 16;
    return (unsigned short)r;
}

// ---------------------------------------------------------------------------
// Kernel A: weight transpose only (36 blocks; pad is folded into conv).
// Stream ordering guarantees completion before conv starts.
// ---------------------------------------------------------------------------
__global__ __launch_bounds__(256) void wb_kernel(
        const float* __restrict__ wq, const float* __restrict__ wk,
        const float* __restrict__ wv, unsigned short* __restrict__ wbT) {
    int base = blockIdx.x * 4096;
    int tid  = threadIdx.x;
    #pragma unroll
    for (int e = 0; e < 16; ++e) {
        int idx = base + e * 256 + tid;      // < 147456
        int t   = idx / 16384;
        int rem = idx % 16384;
        int co  = rem >> 6;
        int ci  = rem & 63;
        float val;
        if (co < 64)        val = wq[(co * 64 + ci) * 9 + t];
        else if (co < 128)  val = wk[((co - 64) * 64 + ci) * 9 + t];
        else                val = wv[((co - 128) * 64 + ci) * 9 + t];
        wbT[(t * 256 + co) * 64 + ci] = f2bf(val);
    }
}

// ---------------------------------------------------------------------------
// Kernel B: conv, full-row tile M96 x N128, pad+convert fused into staging
// (validated exact in R20). grid (192,2) = 384 blocks, XCD-aligned bands.
// ---------------------------------------------------------------------------
__global__ __launch_bounds__(256, 2) void conv_mfma(
        const float* __restrict__ x,
        const unsigned short* __restrict__ wbT,
        const float* __restrict__ bq, const float* __restrict__ bk,
        const float* __restrict__ bv,
        unsigned short* __restrict__ Qb, unsigned short* __restrict__ Kb,
        unsigned short* __restrict__ Vb) {
    __shared__ unsigned short xs[3 * 98 * 72];   // 42336 B (reused as [96][136])
    int bx      = blockIdx.x;                    // 0..191
    int spatial = (bx & 7) * 24 + (bx >> 3);     // XCD-aligned; 24 rows per XCD
    int b    = spatial / 96;
    int h    = spatial % 96;
    int co0  = blockIdx.y * 128;
    int tid  = threadIdx.x;

    // ---- stage 3 rows x 96 interior px from x (float4), halo cols = 0 ----
    #pragma unroll
    for (int g = 0; g < 18; ++g) {
        int i   = tid + g * 256;                 // < 4608
        int r   = i / 1536;
        int rem = i % 1536;
        int ci  = rem / 24;
        int p4  = rem % 24;
        int iy  = h - 1 + r;
        float4 v = make_float4(0.f, 0.f, 0.f, 0.f);
        if (iy >= 0 && iy < HWDIM)
            v = *(const float4*)&x[((b * CIN + ci) * HWDIM + iy) * HWDIM + p4 * 4];
        int bse = (r * 98 + 1 + p4 * 4) * 72 + ci;
        xs[bse]       = f2bf(v.x);
        xs[bse + 72]  = f2bf(v.y);
        xs[bse + 144] = f2bf(v.z);
        xs[bse + 216] = f2bf(v.w);
    }
    if (tid < 192) {   // px 0 and 97 are always outside the image -> zero
        #pragma unroll
        for (int e = 0; e < 2; ++e) {
            int ii  = tid + e * 192;             // < 384
            int r   = ii / 128;
            int rem = ii % 128;
            int ci  = rem >> 1;
            int px  = (rem & 1) ? 97 : 0;
            xs[(r * 98 + px) * 72 + ci] = 0;
        }
    }
    __syncthreads();

    int lane = tid & 63;
    int wv_  = tid >> 6;
    int lw   = lane & 15;
    int ksub = (lane >> 4) * 8;
    int co_t = co0 + wv_ * 32;

    f32x4 acc[6][2];
    #pragma unroll
    for (int m = 0; m < 6; ++m)
        #pragma unroll
        for (int n = 0; n < 2; ++n) acc[m][n] = (f32x4){0.f, 0.f, 0.f, 0.f};

    #pragma unroll
    for (int half = 0; half < 2; ++half) {
        bf16x8 Bf[9][2];
        #pragma unroll
        for (int t = 0; t < 9; ++t) {
            const unsigned short* bp = wbT + ((t * 256 + co_t + lw) * 64) + half * 32 + ksub;
            Bf[t][0] = *(const bf16x8*)(bp);
            Bf[t][1] = *(const bf16x8*)(bp + 16 * 64);
        }
        #pragma unroll
        for (int t = 0; t < 9; ++t) {
            int kh = t / 3, kw = t % 3;
            const unsigned short* ap = xs + (kh * 98 + lw + kw) * 72 + half * 32 + ksub;
            #pragma unroll
            for (int m = 0; m < 6; ++m) {
                bf16x8 A = *(const bf16x8*)(ap + (m * 16) * 72);
                acc[m][0] = __builtin_amdgcn_mfma_f32_16x16x32_bf16(A, Bf[t][0], acc[m][0], 0, 0, 0);
                acc[m][1] = __builtin_amdgcn_mfma_f32_16x16x32_bf16(A, Bf[t][1], acc[m][1], 0, 0, 0);
            }
        }
    }

    // ---- epilogue: bias + f2bf into LDS bounce [96 px][136], b128 stores ----
    __syncthreads();                 // xs reads complete; reuse as xs2
    unsigned short* xs2 = xs;        // [96][136]
    #pragma unroll
    for (int n = 0; n < 2; ++n) {
        int co_f = co_t + n * 16 + lw;
        float bval;
        if (co_f < 64)       bval = bq[co_f];
        else if (co_f < 128) bval = bk[co_f - 64];
        else                 bval = bv[co_f - 128];
        int chl = wv_ * 32 + n * 16 + lw;
        #pragma unroll
        for (int m = 0; m < 6; ++m) {
            int px = m * 16 + ((lane >> 4) << 2);
            #pragma unroll
            for (int r = 0; r < 4; ++r)
                xs2[(px + r) * 136 + chl] = f2bf(acc[m][n][r] + bval);
        }
    }
    __syncthreads();

    #pragma unroll
    for (int e = 0; e < 6; ++e) {
        int i   = tid + e * 256;
        int px  = i >> 4;
        int seg = i & 15;
        uint4 v = *(uint4*)&xs2[px * 136 + seg * 8];
        int pix = b * NPIX + h * HWDIM + px;
        int chl = seg * 8;
        if (co0 == 0) {
            if (chl < 64) *(uint4*)&Qb[pix * CCAT + chl]        = v;
            else          *(uint4*)&Kb[pix * CCAT + (chl - 64)] = v;
        } else {
            *(uint4*)&Vb[pix * CCAT + chl] = v;
        }
    }

    // positional encoding (ch 64..127 of Qb and Kb) by y==0 blocks: 96x64
    if (blockIdx.y == 0) {
        #pragma unroll
        for (int e = 0; e < 24; ++e) {
            int i  = tid + e * 256;          // < 6144
            int c  = i & 63;
            int w  = i >> 6;
            int pos = (c < 32) ? h : w;
            int j   = c & 15;
            float f   = exp2f(-(float)j * 0.83048202372184059f);
            float ang = (float)pos * f;
            float val = ((c & 16) == 0) ? __sinf(ang) : __cosf(ang);
            unsigned short bvv = f2bf(val);
            int pix = b * NPIX + h * HWDIM + w;
            Qb[pix * CCAT + 64 + c] = bvv;
            Kb[pix * CCAT + 64 + c] = bvv;
        }
    }
}

// ---------------------------------------------------------------------------
// Kernel C: natt (champion, byte-identical to R19)
// ---------------------------------------------------------------------------
#define KPAD 136   // bf16 row pad (272 B, 16B-aligned)
#define LGP  114   // f32 logit row stride; MUST be >= 112

__global__ __launch_bounds__(256, 3) void natt_mfma(
        const unsigned short* __restrict__ Qb,
        const unsigned short* __restrict__ Kb,
        const unsigned short* __restrict__ Vb,
        float* __restrict__ out) {
    __shared__ unsigned short Vt[128 * KPAD];   // 34816 B  Vt[ch][nbr^swz]
    __shared__ unsigned short Pb[16 * KPAD];    //  4352 B  Pb[q][nbr]
    __shared__ float Lg[16 * LGP];              //  7296 B   -> 46464 B total

    int bid  = blockIdx.x;                 // 0..1151
    int xcd  = bid & 7;
    int slot = bid >> 3;                   // 0..143
    int s3   = slot % 3;
    int rest = slot / 3;                   // 0..47
    int code = xcd * 3 + s3;               // 0..23
    int b  = code / 12;
    int th = code % 12;
    int tw = rest % 12;
    int gg = rest / 12;                    // 0..3
    int gh = gg & 1;
    int gw = gg >> 1;

    int rh0 = th * 4, rw0 = tw * 4;
    int base_h = min(max(rh0 - 3, 0), 41);
    int base_w = min(max(rw0 - 3, 0), 41);
    int tid = threadIdx.x;
    int lane = tid & 63;
    int wv   = tid >> 6;
    int lw   = lane & 15;
    int ks8  = (lane >> 4) * 8;

    // ---- issue V loads first (consumed after QK^T: latency hidden) ----
    uint4 va[4], vb2[4];
    int   vdst[4];
    #pragma unroll
    for (int j = 0; j < 4; ++j) {
        int c = tid + j * 256;
        bool valid = (j < 3) || (tid < 32);
        int pp = c >> 4, c8 = c & 15;
        int px0 = pp * 2, px1 = px0 + 1;
        int ih0 = px0 / 10, iw0 = px0 - ih0 * 10;
        int ih1 = px1 / 10, iw1 = px1 - ih1 * 10;
        int gp0 = b * NPIX + (gh + 2 * min(base_h + ih0, 47)) * HWDIM + (gw + 2 * min(base_w + iw0, 47));
        int gp1 = b * NPIX + (gh + 2 * min(base_h + ih1, 47)) * HWDIM + (gw + 2 * min(base_w + iw1, 47));
        if (valid) {
            va[j]  = *(const uint4*)(Vb + gp0 * CCAT + c8 * 8);
            vb2[j] = *(const uint4*)(Vb + gp1 * CCAT + c8 * 8);
        }
        vdst[j] = (c8 * 8) * KPAD + (px0 ^ ((c8 & 7) << 3));
    }

    // ---- zero Vt cols 64..127 ----
    for (int i = tid; i < 1024; i += 256) {
        int row = i >> 3, sg = i & 7;
        *(uint4*)(Vt + row * KPAD + 64 + sg * 8) = (uint4){0, 0, 0, 0};
    }

    // ---- QK^T: A (Q row lw) and B (K rows) fragments direct from global ----
    const float scale = 0.08838834764831845f;
    {
        int qi = lw >> 2, qj = lw & 3;
        const unsigned short* qsrc = Qb +
            ((b * NPIX + (gh + 2 * (rh0 + qi)) * HWDIM + (gw + 2 * (rw0 + qj))) * CCAT) + ks8;
        bf16x8 A0 = *(const bf16x8*)(qsrc);
        bf16x8 A1 = *(const bf16x8*)(qsrc + 32);
        bf16x8 A2 = *(const bf16x8*)(qsrc + 64);
        bf16x8 A3 = *(const bf16x8*)(qsrc + 96);

        #pragma unroll
        for (int tt = 0; tt < 2; ++tt) {
            int tile = wv + tt * 4;
            if (tile < 7) {
                int px = min(tile * 16 + lw, 99);
                int ih = px / 10, iw = px - ih * 10;
                const unsigned short* ksrc = Kb +
                    ((b * NPIX + (gh + 2 * min(base_h + ih, 47)) * HWDIM
                               + (gw + 2 * min(base_w + iw, 47))) * CCAT) + ks8;
                bf16x8 B0 = *(const bf16x8*)(ksrc);
                bf16x8 B1 = *(const bf16x8*)(ksrc + 32);
                bf16x8 B2 = *(const bf16x8*)(ksrc + 64);
                bf16x8 B3 = *(const bf16x8*)(ksrc + 96);
                f32x4 acc = (f32x4){0.f, 0.f, 0.f, 0.f};
                __builtin_amdgcn_s_setprio(1);
                acc = __builtin_amdgcn_mfma_f32_16x16x32_bf16(A0, B0, acc, 0, 0, 0);
                acc = __builtin_amdgcn_mfma_f32_16x16x32_bf16(A1, B1, acc, 0, 0, 0);
                acc = __builtin_amdgcn_mfma_f32_16x16x32_bf16(A2, B2, acc, 0, 0, 0);
                acc = __builtin_amdgcn_mfma_f32_16x16x32_bf16(A3, B3, acc, 0, 0, 0);
                __builtin_amdgcn_s_setprio(0);
                #pragma unroll
                for (int r = 0; r < 4; ++r) {
                    int m = (lane >> 4) * 4 + r;
                    Lg[m * LGP + tile * 16 + lw] = acc[r] * scale;
                }
            }
        }
    }
    __syncthreads();   // barrier #0: Lg complete; Vt-zero complete

    // ---- V-pack into Vt ----
    #pragma unroll
    for (int j = 0; j < 4; ++j) {
        bool valid = (j < 3) || (tid < 32);
        if (valid) {
            unsigned short* vp = Vt + vdst[j];
            uint4 v0 = va[j], v1 = vb2[j];
            *(unsigned*)(vp + 0 * KPAD) = (v0.x & 0xFFFFu) | (v1.x << 16);
            *(unsigned*)(vp + 1 * KPAD) = (v0.x >> 16)     | (v1.x & 0xFFFF0000u);
            *(unsigned*)(vp + 2 * KPAD) = (v0.y & 0xFFFFu) | (v1.y << 16);
            *(unsigned*)(vp + 3 * KPAD) = (v0.y >> 16)     | (v1.y & 0xFFFF0000u);
            *(unsigned*)(vp + 4 * KPAD) = (v0.z & 0xFFFFu) | (v1.z << 16);
            *(unsigned*)(vp + 5 * KPAD) = (v0.z >> 16)     | (v1.z & 0xFFFF0000u);
            *(unsigned*)(vp + 6 * KPAD) = (v0.w & 0xFFFFu) | (v1.w << 16);
            *(unsigned*)(vp + 7 * KPAD) = (v0.w >> 16)     | (v1.w & 0xFFFF0000u);
        }
    }

    // ---- softmax (16 threads per query) -> Pb bf16 ----
    int q   = tid >> 4, k16 = tid & 15;
    {
        int qi  = q >> 2, qj = q & 3;
        int rh  = rh0 + qi, rw = rw0 + qj;
        int oh  = min(max(rh - 3, 0), 41) - base_h;
        int ow  = min(max(rw - 3, 0), 41) - base_w;

        float ev[4];
        int   en[4];
        float mx = -1e30f;
        #pragma unroll
        for (int u = 0; u < 4; ++u) {
            int idx = k16 + u * 16;
            if (idx < 49) {
                int i = idx / 7, j = idx - i * 7;
                int n = (oh + i) * 10 + ow + j;
                en[u] = n;
                float l = Lg[q * LGP + n];
                ev[u] = l;
                mx = fmaxf(mx, l);
            } else { en[u] = -1; ev[u] = 0.f; }
        }
        #pragma unroll
        for (int off = 8; off > 0; off >>= 1) mx = fmaxf(mx, __shfl_xor(mx, off));
        float s = 0.f;
        #pragma unroll
        for (int u = 0; u < 4; ++u)
            if (en[u] >= 0) { ev[u] = __expf(ev[u] - mx); s += ev[u]; }
        #pragma unroll
        for (int off = 8; off > 0; off >>= 1) s += __shfl_xor(s, off);
        float rs = 1.0f / s;
        *(uint4*)(Pb + q * KPAD + k16 * 8) = (uint4){0, 0, 0, 0};
        #pragma unroll
        for (int u = 0; u < 4; ++u)
            if (en[u] >= 0) Pb[q * KPAD + en[u]] = f2bf(ev[u] * rs);
    }
    __syncthreads();   // barrier #1: Pb and Vt ready

    // ---- PV MFMA: wave handles ch-tiles 2wv, 2wv+1 ----
    bf16x8 A4[4];
    #pragma unroll
    for (int kk = 0; kk < 4; ++kk)
        A4[kk] = *(const bf16x8*)(Pb + lw * KPAD + kk * 32 + ks8);

    __builtin_amdgcn_s_setprio(1);
    #pragma unroll
    for (int tt = 0; tt < 2; ++tt) {
        int tile = wv * 2 + tt;
        int row  = tile * 16 + lw;
        int sw   = ((row >> 3) & 7) << 3;
        const unsigned short* vrow = Vt + row * KPAD;
        f32x4 acc = (f32x4){0.f, 0.f, 0.f, 0.f};
        #pragma unroll
        for (int kk = 0; kk < 4; ++kk) {
            bf16x8 Bf = *(const bf16x8*)(vrow + ((kk * 32 + ks8) ^ sw));
            acc = __builtin_amdgcn_mfma_f32_16x16x32_bf16(A4[kk], Bf, acc, 0, 0, 0);
        }
        int ch = row;
        #pragma unroll
        for (int r = 0; r < 4; ++r) {
            int qq = (lane >> 4) * 4 + r;
            int qi = qq >> 2, qj = qq & 3;
            int gp = b * NPIX + (gh + 2 * (rh0 + qi)) * HWDIM + (gw + 2 * (rw0 + qj));
            out[gp * CCAT + ch] = acc[r];
        }
    }
    __builtin_amdgcn_s_setprio(0);
}

// ---------------------------------------------------------------------------
extern "C" void kernel_launch(void* const* d_in, const int* in_sizes, int n_in,
                              void* d_out, int out_size, void* d_ws, size_t ws_size,
                              hipStream_t stream) {
    const float* x  = (const float*)d_in[0];
    const float* wq = (const float*)d_in[1];
    const float* bq = (const float*)d_in[2];
    const float* wk = (const float*)d_in[3];
    const float* bk = (const float*)d_in[4];
    const float* wv = (const float*)d_in[5];
    const float* bv = (const float*)d_in[6];

    unsigned short* ws = (unsigned short*)d_ws;
    unsigned short* Qb  = ws;                              // 2359296 bf16
    unsigned short* Kb  = Qb + BATCH * NPIX * CCAT;
    unsigned short* Vb  = Kb + BATCH * NPIX * CCAT;
    unsigned short* wbT = Vb + BATCH * NPIX * CCAT;        // 147456 bf16

    hipLaunchKernelGGL(wb_kernel, dim3(36), dim3(256), 0, stream,
                       wq, wk, wv, wbT);
    hipLaunchKernelGGL(conv_mfma, dim3(192, 2), dim3(256), 0, stream,
                       x, wbT, bq, bk, bv, Qb, Kb, Vb);
    hipLaunchKernelGGL(natt_mfma, dim3(1152), dim3(256), 0, stream,
                       Qb, Kb, Vb, (float*)d_out);
}

// Round 22
// 42.503 us; speedup vs baseline: 1.1416x; 1.0218x over previous
//
#include <hip/hip_runtime.h>
#include <math.h>

#define HWDIM 96
#define NPIX (HWDIM*HWDIM)     // 9216
#define BATCH 2
#define CIN 64
#define CCAT 128
#define PADW 98                // 96 + 2 halo

typedef __attribute__((ext_vector_type(8))) short bf16x8;
typedef __attribute__((ext_vector_type(4))) float f32x4;

__device__ __forceinline__ unsigned short f2bf(float f) {
    unsigned u = __builtin_bit_cast(unsigned, f);
    unsigned r = (u + 0x7FFFu + ((u >> 16) & 1u)) >> 16;
    return (unsigned short)r;
}

// ---------------------------------------------------------------------------
// Kernel A: prep (R19 champion): XCD-aligned pad + weight transpose
// ---------------------------------------------------------------------------
__global__ __launch_bounds__(256) void prep_kernel(
        const float* __restrict__ x,
        const float* __restrict__ wq, const float* __restrict__ wk,
        const float* __restrict__ wv,
        unsigned short* __restrict__ xp, unsigned short* __restrict__ wbT) {
    int bid = blockIdx.x;
    int tid = threadIdx.x;
    if (bid < 200) {
        int k    = bid & 7;
        int slot = bid >> 3;              // 0..24
        int m    = k & 3;
        int cnt  = 25 - (m >> 1);         // m=0,1:25  m=2,3:24
        if (slot >= cnt) return;
        int start = 25 * m - (m == 3 ? 1 : 0);   // 0,25,50,74
        int b  = k >> 2;
        int hp = start + slot;            // 0..97
        __shared__ float xls[64][97];
        bool interior = (hp >= 1 && hp <= HWDIM);
        if (interior) {
            int h = hp - 1;
            for (int idx = tid; idx < 64 * HWDIM; idx += 256) {
                int ci = idx / HWDIM;
                int w  = idx % HWDIM;
                xls[ci][w] = x[((b * CIN + ci) * HWDIM + h) * HWDIM + w];
            }
        }
        __syncthreads();
        for (int idx = tid; idx < PADW * 64; idx += 256) {
            int wp = idx / 64;
            int ci = idx % 64;
            float v = 0.f;
            if (interior && wp >= 1 && wp <= HWDIM) v = xls[ci][wp - 1];
            xp[((b * PADW + hp) * PADW + wp) * 64 + ci] = f2bf(v);
        }
    } else {
        int base = (bid - 200) * 4096;
        #pragma unroll
        for (int e = 0; e < 16; ++e) {
            int idx = base + e * 256 + tid;      // < 147456
            int t   = idx / (256 * 64);
            int rem = idx % (256 * 64);
            int co  = rem / 64;
            int ci  = rem % 64;
            float val;
            if (co < 64)        val = wq[(co * 64 + ci) * 9 + t];
            else if (co < 128)  val = wk[((co - 64) * 64 + ci) * 9 + t];
            else                val = wv[((co - 128) * 64 + ci) * 9 + t];
            wbT[(t * 256 + co) * 64 + ci] = f2bf(val);
        }
    }
}

// ---------------------------------------------------------------------------
// Kernel B: conv (R19 champion): full-row tile M96 x N128, grid (192,2)
// ---------------------------------------------------------------------------
__global__ __launch_bounds__(256, 2) void conv_mfma(
        const unsigned short* __restrict__ xp,
        const unsigned short* __restrict__ wbT,
        const float* __restrict__ bq, const float* __restrict__ bk,
        const float* __restrict__ bv,
        unsigned short* __restrict__ Qb, unsigned short* __restrict__ Kb,
        unsigned short* __restrict__ Vb) {
    __shared__ unsigned short xs[3 * 98 * 72];   // 42336 B (reused as [96][136])
    int bx      = blockIdx.x;                    // 0..191
    int spatial = (bx & 7) * 24 + (bx >> 3);     // XCD-aligned; 24 rows per XCD
    int b    = spatial / 96;
    int h    = spatial % 96;
    int co0  = blockIdx.y * 128;
    int tid  = threadIdx.x;

    // stage 3 padded rows x 98 px x 64 ci = 2352 16B chunks (load-then-write)
    {
        uint4 rv[10];
        int   ldst[10];
        #pragma unroll
        for (int i = 0; i < 10; ++i) {
            int idx = tid + i * 256;
            bool valid = (i < 9) || (tid < 48);   // 2352 = 9*256 + 48
            int r    = idx / 784;                 // 98*8 chunks per row
            int rem  = idx % 784;
            int wp   = rem >> 3;
            int c8   = rem & 7;
            if (valid)
                rv[i] = *(const uint4*)&xp[(((b * PADW) + h + r) * PADW + wp) * 64 + c8 * 8];
            ldst[i] = (r * 98 + wp) * 72 + c8 * 8;
        }
        #pragma unroll
        for (int i = 0; i < 10; ++i) {
            bool valid = (i < 9) || (tid < 48);
            if (valid) *(uint4*)&xs[ldst[i]] = rv[i];
        }
    }
    __syncthreads();

    int lane = tid & 63;
    int wv   = tid >> 6;
    int lw   = lane & 15;
    int ksub = (lane >> 4) * 8;
    int co_t = co0 + wv * 32;

    f32x4 acc[6][2];
    #pragma unroll
    for (int m = 0; m < 6; ++m)
        #pragma unroll
        for (int n = 0; n < 2; ++n) acc[m][n] = (f32x4){0.f, 0.f, 0.f, 0.f};

    #pragma unroll
    for (int half = 0; half < 2; ++half) {
        bf16x8 Bf[9][2];
        #pragma unroll
        for (int t = 0; t < 9; ++t) {
            const unsigned short* bp = wbT + ((t * 256 + co_t + lw) * 64) + half * 32 + ksub;
            Bf[t][0] = *(const bf16x8*)(bp);
            Bf[t][1] = *(const bf16x8*)(bp + 16 * 64);
        }
        #pragma unroll
        for (int t = 0; t < 9; ++t) {
            int kh = t / 3, kw = t % 3;
            const unsigned short* ap = xs + (kh * 98 + lw + kw) * 72 + half * 32 + ksub;
            #pragma unroll
            for (int m = 0; m < 6; ++m) {
                bf16x8 A = *(const bf16x8*)(ap + (m * 16) * 72);
                acc[m][0] = __builtin_amdgcn_mfma_f32_16x16x32_bf16(A, Bf[t][0], acc[m][0], 0, 0, 0);
                acc[m][1] = __builtin_amdgcn_mfma_f32_16x16x32_bf16(A, Bf[t][1], acc[m][1], 0, 0, 0);
            }
        }
    }

    // ---- epilogue: bias + f2bf into LDS bounce [96 px][136], b128 stores ----
    __syncthreads();                 // xs reads complete; reuse as xs2
    unsigned short* xs2 = xs;        // [96][136]
    #pragma unroll
    for (int n = 0; n < 2; ++n) {
        int co_f = co_t + n * 16 + lw;
        float bval;
        if (co_f < 64)       bval = bq[co_f];
        else if (co_f < 128) bval = bk[co_f - 64];
        else                 bval = bv[co_f - 128];
        int chl = wv * 32 + n * 16 + lw;
        #pragma unroll
        for (int m = 0; m < 6; ++m) {
            int px = m * 16 + ((lane >> 4) << 2);
            #pragma unroll
            for (int r = 0; r < 4; ++r)
                xs2[(px + r) * 136 + chl] = f2bf(acc[m][n][r] + bval);
        }
    }
    __syncthreads();

    // coalesced stores: 96 px x 16 segs = 1536 chunks, 6 per thread
    #pragma unroll
    for (int e = 0; e < 6; ++e) {
        int i   = tid + e * 256;
        int px  = i >> 4;
        int seg = i & 15;
        uint4 v = *(uint4*)&xs2[px * 136 + seg * 8];
        int pix = b * NPIX + h * HWDIM + px;
        int chl = seg * 8;
        if (co0 == 0) {
            if (chl < 64) *(uint4*)&Qb[pix * CCAT + chl]        = v;
            else          *(uint4*)&Kb[pix * CCAT + (chl - 64)] = v;
        } else {
            *(uint4*)&Vb[pix * CCAT + chl] = v;
        }
    }

    // positional encoding (ch 64..127 of Qb and Kb) by y==0 blocks: 96x64
    if (blockIdx.y == 0) {
        #pragma unroll
        for (int e = 0; e < 24; ++e) {
            int i  = tid + e * 256;          // < 6144
            int c  = i & 63;
            int w  = i >> 6;
            int pos = (c < 32) ? h : w;
            int j   = c & 15;
            float f   = exp2f(-(float)j * 0.83048202372184059f);
            float ang = (float)pos * f;
            float val = ((c & 16) == 0) ? __sinf(ang) : __cosf(ang);
            unsigned short bvv = f2bf(val);
            int pix = b * NPIX + h * HWDIM + w;
            Qb[pix * CCAT + 64 + c] = bvv;
            Kb[pix * CCAT + 64 + c] = bvv;
        }
    }
}

// ---------------------------------------------------------------------------
// Kernel C: natt (R19 champion, byte-identical)
// ---------------------------------------------------------------------------
#define KPAD 136   // bf16 row pad (272 B, 16B-aligned)
#define LGP  114   // f32 logit row stride; MUST be >= 112

__global__ __launch_bounds__(256, 3) void natt_mfma(
        const unsigned short* __restrict__ Qb,
        const unsigned short* __restrict__ Kb,
        const unsigned short* __restrict__ Vb,
        float* __restrict__ out) {
    __shared__ unsigned short Vt[128 * KPAD];   // 34816 B  Vt[ch][nbr^swz]
    __shared__ unsigned short Pb[16 * KPAD];    //  4352 B  Pb[q][nbr]
    __shared__ float Lg[16 * LGP];              //  7296 B   -> 46464 B total

    int bid  = blockIdx.x;                 // 0..1151
    int xcd  = bid & 7;
    int slot = bid >> 3;                   // 0..143
    int s3   = slot % 3;
    int rest = slot / 3;                   // 0..47
    int code = xcd * 3 + s3;               // 0..23
    int b  = code / 12;
    int th = code % 12;
    int tw = rest % 12;
    int gg = rest / 12;                    // 0..3
    int gh = gg & 1;
    int gw = gg >> 1;

    int rh0 = th * 4, rw0 = tw * 4;
    int base_h = min(max(rh0 - 3, 0), 41);
    int base_w = min(max(rw0 - 3, 0), 41);
    int tid = threadIdx.x;
    int lane = tid & 63;
    int wv   = tid >> 6;
    int lw   = lane & 15;
    int ks8  = (lane >> 4) * 8;

    // ---- issue V loads first (consumed after QK^T: latency hidden) ----
    uint4 va[4], vb2[4];
    int   vdst[4];
    #pragma unroll
    for (int j = 0; j < 4; ++j) {
        int c = tid + j * 256;
        bool valid = (j < 3) || (tid < 32);
        int pp = c >> 4, c8 = c & 15;
        int px0 = pp * 2, px1 = px0 + 1;
        int ih0 = px0 / 10, iw0 = px0 - ih0 * 10;
        int ih1 = px1 / 10, iw1 = px1 - ih1 * 10;
        int gp0 = b * NPIX + (gh + 2 * min(base_h + ih0, 47)) * HWDIM + (gw + 2 * min(base_w + iw0, 47));
        int gp1 = b * NPIX + (gh + 2 * min(base_h + ih1, 47)) * HWDIM + (gw + 2 * min(base_w + iw1, 47));
        if (valid) {
            va[j]  = *(const uint4*)(Vb + gp0 * CCAT + c8 * 8);
            vb2[j] = *(const uint4*)(Vb + gp1 * CCAT + c8 * 8);
        }
        vdst[j] = (c8 * 8) * KPAD + (px0 ^ ((c8 & 7) << 3));
    }

    // ---- zero Vt cols 64..127 ----
    for (int i = tid; i < 1024; i += 256) {
        int row = i >> 3, sg = i & 7;
        *(uint4*)(Vt + row * KPAD + 64 + sg * 8) = (uint4){0, 0, 0, 0};
    }

    // ---- QK^T: A (Q row lw) and B (K rows) fragments direct from global ----
    const float scale = 0.08838834764831845f;
    {
        int qi = lw >> 2, qj = lw & 3;
        const unsigned short* qsrc = Qb +
            ((b * NPIX + (gh + 2 * (rh0 + qi)) * HWDIM + (gw + 2 * (rw0 + qj))) * CCAT) + ks8;
        bf16x8 A0 = *(const bf16x8*)(qsrc);
        bf16x8 A1 = *(const bf16x8*)(qsrc + 32);
        bf16x8 A2 = *(const bf16x8*)(qsrc + 64);
        bf16x8 A3 = *(const bf16x8*)(qsrc + 96);

        #pragma unroll
        for (int tt = 0; tt < 2; ++tt) {
            int tile = wv + tt * 4;
            if (tile < 7) {
                int px = min(tile * 16 + lw, 99);
                int ih = px / 10, iw = px - ih * 10;
                const unsigned short* ksrc = Kb +
                    ((b * NPIX + (gh + 2 * min(base_h + ih, 47)) * HWDIM
                               + (gw + 2 * min(base_w + iw, 47))) * CCAT) + ks8;
                bf16x8 B0 = *(const bf16x8*)(ksrc);
                bf16x8 B1 = *(const bf16x8*)(ksrc + 32);
                bf16x8 B2 = *(const bf16x8*)(ksrc + 64);
                bf16x8 B3 = *(const bf16x8*)(ksrc + 96);
                f32x4 acc = (f32x4){0.f, 0.f, 0.f, 0.f};
                __builtin_amdgcn_s_setprio(1);
                acc = __builtin_amdgcn_mfma_f32_16x16x32_bf16(A0, B0, acc, 0, 0, 0);
                acc = __builtin_amdgcn_mfma_f32_16x16x32_bf16(A1, B1, acc, 0, 0, 0);
                acc = __builtin_amdgcn_mfma_f32_16x16x32_bf16(A2, B2, acc, 0, 0, 0);
                acc = __builtin_amdgcn_mfma_f32_16x16x32_bf16(A3, B3, acc, 0, 0, 0);
                __builtin_amdgcn_s_setprio(0);
                #pragma unroll
                for (int r = 0; r < 4; ++r) {
                    int m = (lane >> 4) * 4 + r;
                    Lg[m * LGP + tile * 16 + lw] = acc[r] * scale;
                }
            }
        }
    }
    __syncthreads();   // barrier #0: Lg complete; Vt-zero complete

    // ---- V-pack into Vt ----
    #pragma unroll
    for (int j = 0; j < 4; ++j) {
        bool valid = (j < 3) || (tid < 32);
        if (valid) {
            unsigned short* vp = Vt + vdst[j];
            uint4 v0 = va[j], v1 = vb2[j];
            *(unsigned*)(vp + 0 * KPAD) = (v0.x & 0xFFFFu) | (v1.x << 16);
            *(unsigned*)(vp + 1 * KPAD) = (v0.x >> 16)     | (v1.x & 0xFFFF0000u);
            *(unsigned*)(vp + 2 * KPAD) = (v0.y & 0xFFFFu) | (v1.y << 16);
            *(unsigned*)(vp + 3 * KPAD) = (v0.y >> 16)     | (v1.y & 0xFFFF0000u);
            *(unsigned*)(vp + 4 * KPAD) = (v0.z & 0xFFFFu) | (v1.z << 16);
            *(unsigned*)(vp + 5 * KPAD) = (v0.z >> 16)     | (v1.z & 0xFFFF0000u);
            *(unsigned*)(vp + 6 * KPAD) = (v0.w & 0xFFFFu) | (v1.w << 16);
            *(unsigned*)(vp + 7 * KPAD) = (v0.w >> 16)     | (v1.w & 0xFFFF0000u);
        }
    }

    // ---- softmax (16 threads per query) -> Pb bf16 ----
    int q   = tid >> 4, k16 = tid & 15;
    {
        int qi  = q >> 2, qj = q & 3;
        int rh  = rh0 + qi, rw = rw0 + qj;
        int oh  = min(max(rh - 3, 0), 41) - base_h;
        int ow  = min(max(rw - 3, 0), 41) - base_w;

        float ev[4];
        int   en[4];
        float mx = -1e30f;
        #pragma unroll
        for (int u = 0; u < 4; ++u) {
            int idx = k16 + u * 16;
            if (idx < 49) {
                int i = idx / 7, j = idx - i * 7;
                int n = (oh + i) * 10 + ow + j;
                en[u] = n;
                float l = Lg[q * LGP + n];
                ev[u] = l;
                mx = fmaxf(mx, l);
            } else { en[u] = -1; ev[u] = 0.f; }
        }
        #pragma unroll
        for (int off = 8; off > 0; off >>= 1) mx = fmaxf(mx, __shfl_xor(mx, off));
        float s = 0.f;
        #pragma unroll
        for (int u = 0; u < 4; ++u)
            if (en[u] >= 0) { ev[u] = __expf(ev[u] - mx); s += ev[u]; }
        #pragma unroll
        for (int off = 8; off > 0; off >>= 1) s += __shfl_xor(s, off);
        float rs = 1.0f / s;
        *(uint4*)(Pb + q * KPAD + k16 * 8) = (uint4){0, 0, 0, 0};
        #pragma unroll
        for (int u = 0; u < 4; ++u)
            if (en[u] >= 0) Pb[q * KPAD + en[u]] = f2bf(ev[u] * rs);
    }
    __syncthreads();   // barrier #1: Pb and Vt ready

    // ---- PV MFMA: wave handles ch-tiles 2wv, 2wv+1 ----
    bf16x8 A4[4];
    #pragma unroll
    for (int kk = 0; kk < 4; ++kk)
        A4[kk] = *(const bf16x8*)(Pb + lw * KPAD + kk * 32 + ks8);

    __builtin_amdgcn_s_setprio(1);
    #pragma unroll
    for (int tt = 0; tt < 2; ++tt) {
        int tile = wv * 2 + tt;
        int row  = tile * 16 + lw;
        int sw   = ((row >> 3) & 7) << 3;
        const unsigned short* vrow = Vt + row * KPAD;
        f32x4 acc = (f32x4){0.f, 0.f, 0.f, 0.f};
        #pragma unroll
        for (int kk = 0; kk < 4; ++kk) {
            bf16x8 Bf = *(const bf16x8*)(vrow + ((kk * 32 + ks8) ^ sw));
            acc = __builtin_amdgcn_mfma_f32_16x16x32_bf16(A4[kk], Bf, acc, 0, 0, 0);
        }
        int ch = row;
        #pragma unroll
        for (int r = 0; r < 4; ++r) {
            int qq = (lane >> 4) * 4 + r;
            int qi = qq >> 2, qj = qq & 3;
            int gp = b * NPIX + (gh + 2 * (rh0 + qi)) * HWDIM + (gw + 2 * (rw0 + qj));
            out[gp * CCAT + ch] = acc[r];
        }
    }
    __builtin_amdgcn_s_setprio(0);
}

// ---------------------------------------------------------------------------
extern "C" void kernel_launch(void* const* d_in, const int* in_sizes, int n_in,
                              void* d_out, int out_size, void* d_ws, size_t ws_size,
                              hipStream_t stream) {
    const float* x  = (const float*)d_in[0];
    const float* wq = (const float*)d_in[1];
    const float* bq = (const float*)d_in[2];
    const float* wk = (const float*)d_in[3];
    const float* bk = (const float*)d_in[4];
    const float* wv = (const float*)d_in[5];
    const float* bv = (const float*)d_in[6];

    unsigned short* ws = (unsigned short*)d_ws;
    unsigned short* Qb  = ws;                              // 2359296 bf16
    unsigned short* Kb  = Qb + BATCH * NPIX * CCAT;
    unsigned short* Vb  = Kb + BATCH * NPIX * CCAT;
    unsigned short* xp  = Vb + BATCH * NPIX * CCAT;        // 2*98*98*64
    unsigned short* wbT = xp + BATCH * PADW * PADW * 64;   // 147456

    hipLaunchKernelGGL(prep_kernel, dim3(236), dim3(256), 0, stream,
                       x, wq, wk, wv, xp, wbT);
    hipLaunchKernelGGL(conv_mfma, dim3(192, 2), dim3(256), 0, stream,
                       xp, wbT, bq, bk, bv, Qb, Kb, Vb);
    hipLaunchKernelGGL(natt_mfma, dim3(1152), dim3(256), 0, stream,
                       Qb, Kb, Vb, (float*)d_out);
}